// Round 15
// baseline (245.080 us; speedup 1.0000x reference)
//
#include <hip/hip_runtime.h>
#include <hip/hip_bf16.h>

typedef __bf16 bf16;
typedef __attribute__((ext_vector_type(8))) __bf16 bf16x8;
typedef __attribute__((ext_vector_type(4))) float f32x4;

#define S_LEN 2048
#define DM 2048
#define NH 32
#define HD 64
#define QKV_LD 6144
// SCALE * log2(e): QK^T scores land directly in log2 domain
#define SCALE2 0.18033688011112042f
#define DEFER_THR 8.0f

// 2^x via v_exp_f32 (gfx9 v_exp IS base-2 exp).
__device__ __forceinline__ float fast_exp2(float x) {
  return __builtin_amdgcn_exp2f(x);
}

// Async global->LDS, 16B per lane. LDS dest must be wave-uniform base; data
// lands at base + lane*16.
__device__ __forceinline__ void gload_lds16(const bf16* g, const bf16* l) {
  __builtin_amdgcn_global_load_lds(
      (const __attribute__((address_space(1))) void*)(uintptr_t)g,
      (__attribute__((address_space(3))) void*)(uint32_t)(uintptr_t)l,
      16, 0, 0);
}

// Compile-time counted vmcnt (inline asm needs a literal).
template <int N>
__device__ __forceinline__ void waitcnt_vm() {
  if constexpr (N == 0)      asm volatile("s_waitcnt vmcnt(0)" ::: "memory");
  else if constexpr (N == 4) asm volatile("s_waitcnt vmcnt(4)" ::: "memory");
  else if constexpr (N == 5) asm volatile("s_waitcnt vmcnt(5)" ::: "memory");
  else if constexpr (N == 6) asm volatile("s_waitcnt vmcnt(6)" ::: "memory");
  else if constexpr (N == 7) asm volatile("s_waitcnt vmcnt(7)" ::: "memory");
  else if constexpr (N == 8) asm volatile("s_waitcnt vmcnt(8)" ::: "memory");
  else static_assert(N == 0, "add vmcnt case");
}

// DPP cross-lane move (VALU pipe — no LDS latency).
template <int CTRL>
__device__ __forceinline__ float fdpp(float x) {
  return __builtin_bit_cast(float,
      __builtin_amdgcn_update_dpp(0, __builtin_bit_cast(int, x), CTRL, 0xF, 0xF, true));
}
// Exact 16-lane butterfly all-reduce: masks {1,2,7,15} are GF(2)-independent.
__device__ __forceinline__ float red16_max(float x) {
  x = fmaxf(x, fdpp<0xB1>(x));    // quad_perm [1,0,3,2]  : xor 1
  x = fmaxf(x, fdpp<0x4E>(x));    // quad_perm [2,3,0,1]  : xor 2
  x = fmaxf(x, fdpp<0x141>(x));   // row_half_mirror      : xor 7
  x = fmaxf(x, fdpp<0x140>(x));   // row_mirror           : xor 15
  return x;
}
__device__ __forceinline__ float red16_sum(float x) {
  x += fdpp<0xB1>(x);
  x += fdpp<0x4E>(x);
  x += fdpp<0x141>(x);
  x += fdpp<0x140>(x);
  return x;
}

// ---------------------------------------------------------------------------
// Fused f32 -> bf16 conversion over three arrays (one launch, grid-stride)
// ---------------------------------------------------------------------------
__global__ __launch_bounds__(256) void cvt3_f32_bf16(
    const float* __restrict__ s0, bf16* __restrict__ d0, const int n0,
    const float* __restrict__ s1, bf16* __restrict__ d1, const int n1,
    const float* __restrict__ s2, bf16* __restrict__ d2, const int n2)
{
  const int total = n0 + n1 + n2;
  const int stride = gridDim.x * blockDim.x;
  for (int i = blockIdx.x * blockDim.x + threadIdx.x; i < total; i += stride) {
    const float* s; bf16* d; int j = i;
    if (j < n0)            { s = s0; d = d0; }
    else if (j - n0 < n1)  { s = s1; d = d1; j -= n0; }
    else                   { s = s2; d = d2; j -= n0 + n1; }
    const f32x4 a = *(const f32x4*)(s + (size_t)j * 8);
    const f32x4 b = *(const f32x4*)(s + (size_t)j * 8 + 4);
    bf16x8 r;
    r[0] = (bf16)a[0]; r[1] = (bf16)a[1]; r[2] = (bf16)a[2]; r[3] = (bf16)a[3];
    r[4] = (bf16)b[0]; r[5] = (bf16)b[1]; r[6] = (bf16)b[2]; r[7] = (bf16)b[3];
    *(bf16x8*)(d + (size_t)j * 8) = r;
  }
}

// ---------------------------------------------------------------------------
// Pipelined GEMM: C[M][N] = A @ W^T + bias.  BK=64, double-buffered LDS,
// depth-1 counted-vmcnt pipeline, T2 swizzle (rule #21), 2 blocks/CU.
// ---------------------------------------------------------------------------
template <int BM, int BN, int WRN, int WCN, int NT, int MINW, typename TO>
__global__ __launch_bounds__(NT, MINW) void gemm_pipe(
    const bf16* __restrict__ A, const bf16* __restrict__ W,
    const float* __restrict__ bias, TO* __restrict__ C,
    const int M, const int N, const int K)
{
  constexpr int WM = BM / WRN, WN = BN / WCN;
  constexpr int MI = WM / 16, NI = WN / 16;
  constexpr int CA = (BM * 64 * 2) / (NT * 16);   // staging chunks (A)
  constexpr int CB = (BN * 64 * 2) / (NT * 16);   // staging chunks (B)
  constexpr int BUFE = (BM + BN) * 64;            // elems per buffer
  __shared__ __align__(16) bf16 lds[2 * BUFE];
  const int tid  = threadIdx.x;
  const int lane = tid & 63;
  const int wid  = tid >> 6;
  const int wr = wid / WCN, wc = wid % WCN;
  const int row0 = blockIdx.y * BM, col0 = blockIdx.x * BN;
  const int lq = lane & 15, seg = lane >> 4;

  const f32x4 fz = {0.f, 0.f, 0.f, 0.f};
  f32x4 acc[MI][NI];
#pragma unroll
  for (int i = 0; i < MI; ++i)
#pragma unroll
    for (int j = 0; j < NI; ++j) acc[i][j] = fz;

  auto stage = [&](const int kt, const int b) {
    const int k0 = kt << 6;
    bf16* Ab = lds + b * BUFE;
    bf16* Bb = Ab + BM * 64;
#pragma unroll
    for (int c = 0; c < CA; ++c) {
      const int off16 = c * NT + tid;              // 16B-unit linear index
      const int row = off16 >> 3;                  // 128B rows (BK=64 bf16)
      const int ch  = (off16 & 7) ^ (row & 7);     // pre-swizzled source
      gload_lds16(A + (size_t)(row0 + row) * K + k0 + (ch << 3),
                  Ab + (size_t)(c * NT + (wid << 6)) * 8);
    }
#pragma unroll
    for (int c = 0; c < CB; ++c) {
      const int off16 = c * NT + tid;
      const int row = off16 >> 3;
      const int ch  = (off16 & 7) ^ (row & 7);
      gload_lds16(W + (size_t)(col0 + row) * K + k0 + (ch << 3),
                  Bb + (size_t)(c * NT + (wid << 6)) * 8);
    }
  };

  const int nt = K >> 6;
  stage(0, 0);

  for (int t = 0; t < nt; ++t) {
    asm volatile("" ::: "memory");
    __builtin_amdgcn_s_barrier();                  // frees buf (t+1)&1
    asm volatile("" ::: "memory");
    if (t + 1 < nt) {
      stage(t + 1, (t + 1) & 1);                   // loads fly across tile t
      waitcnt_vm<CA + CB>();                       // tile-t loads landed (mine)
    } else {
      waitcnt_vm<0>();                             // tail drain
    }
    __builtin_amdgcn_s_barrier();                  // tile t landed (all waves)
    asm volatile("" ::: "memory");

    const bf16* Ab = lds + (t & 1) * BUFE;
    const bf16* Bb = Ab + BM * 64;
#pragma unroll
    for (int kk = 0; kk < 2; ++kk) {               // K=64 as 2 x K32
      bf16x8 af[MI], bfr[NI];
#pragma unroll
      for (int i = 0; i < MI; ++i) {
        const int row = wr * WM + (i << 4) + lq;
        af[i] = *(const bf16x8*)(Ab + row * 64 +
                 ((((kk << 2) + seg) ^ (row & 7)) << 3));
      }
#pragma unroll
      for (int j = 0; j < NI; ++j) {
        const int row = wc * WN + (j << 4) + lq;
        bfr[j] = *(const bf16x8*)(Bb + row * 64 +
                 ((((kk << 2) + seg) ^ (row & 7)) << 3));
      }
      __builtin_amdgcn_s_setprio(1);
#pragma unroll
      for (int i = 0; i < MI; ++i)
#pragma unroll
        for (int j = 0; j < NI; ++j)
          acc[i][j] = __builtin_amdgcn_mfma_f32_16x16x32_bf16(af[i], bfr[j], acc[i][j], 0, 0, 0);
      __builtin_amdgcn_s_setprio(0);
    }
  }

  // Epilogue: C/D layout row=(lane>>4)*4+r, col=lane&15
#pragma unroll
  for (int j = 0; j < NI; ++j) {
    const int col = col0 + wc * WN + (j << 4) + lq;
    const float bv = bias[col];
#pragma unroll
    for (int i = 0; i < MI; ++i) {
      const int rbase = row0 + wr * WM + (i << 4) + (seg << 2);
#pragma unroll
      for (int r = 0; r < 4; ++r)
        C[(size_t)(rbase + r) * N + col] = (TO)(acc[i][j][r] + bv);
    }
  }
}

// ---------------------------------------------------------------------------
// Per-q-tile flash state (one 16-row slice per wave).
// ---------------------------------------------------------------------------
struct QTile {
  bf16x8 qf[2];    // pre-scaled by SCALE*log2e
  f32x4  o[4];
  float  m[4], l[4];
};

__device__ __forceinline__ void qtile_init(QTile& st, const bf16* Qg,
                                           const int lq, const int seg) {
  const bf16x8 r0 = *(const bf16x8*)(Qg + (size_t)lq * QKV_LD + seg * 8);
  const bf16x8 r1 = *(const bf16x8*)(Qg + (size_t)lq * QKV_LD + 32 + seg * 8);
#pragma unroll
  for (int j = 0; j < 8; ++j) {
    st.qf[0][j] = (bf16)((float)r0[j] * SCALE2);
    st.qf[1][j] = (bf16)((float)r1[j] * SCALE2);
  }
  const f32x4 fz = {0.f, 0.f, 0.f, 0.f};
#pragma unroll
  for (int r = 0; r < 4; ++r) { st.o[r] = fz; st.m[r] = -1e30f; st.l[r] = 0.f; }
}

// QK^T -> mask -> online softmax (log2 domain, defer-max) -> P -> PV.
__device__ __forceinline__ void qtile_step(
    QTile& st, const int qb, const int nt,
    const int ws, const int lq, const int seg,
    const bf16 (&Ks)[64][64], const bf16 (&Vt)[64][64], bf16 (&Psw)[16][64])
{
  const f32x4 fz = {0.f, 0.f, 0.f, 0.f};
  f32x4 s[4];
  __builtin_amdgcn_s_setprio(1);
#pragma unroll
  for (int ct = 0; ct < 4; ++ct) {
    s[ct] = fz;
#pragma unroll
    for (int ks = 0; ks < 2; ++ks) {
      const int blk = ((ks << 2) + seg) ^ (lq & 7);
      const bf16x8 kf = *(const bf16x8*)(&Ks[(ct << 4) + lq][blk << 3]);
      s[ct] = __builtin_amdgcn_mfma_f32_16x16x32_bf16(st.qf[ks], kf, s[ct], 0, 0, 0);
    }
  }
  __builtin_amdgcn_s_setprio(0);

  // causal mask (diagonal tile only); scores already scaled via Q
  if (nt == qb) {
#pragma unroll
    for (int ct = 0; ct < 4; ++ct) {
      const int key = (nt << 6) + (ct << 4) + lq;
#pragma unroll
      for (int r = 0; r < 4; ++r) {
        const int qrow = (qb << 6) + (ws << 4) + (seg << 2) + r;
        if (key > qrow) s[ct][r] = -1e30f;
      }
    }
  }

  // online softmax, log2 domain, defer-max (skip rescale within THR)
#pragma unroll
  for (int r = 0; r < 4; ++r) {
    float tm = fmaxf(fmaxf(s[0][r], s[1][r]), fmaxf(s[2][r], s[3][r]));
    tm = red16_max(tm);
    if (tm > st.m[r] + DEFER_THR) {      // rescale path (rare)
      const float sc = fast_exp2(st.m[r] - tm);
      st.m[r] = tm;
      st.l[r] *= sc;
#pragma unroll
      for (int dt = 0; dt < 4; ++dt) st.o[dt][r] *= sc;
    }
    float rs = 0.f;
#pragma unroll
    for (int ct = 0; ct < 4; ++ct) {
      const float p = fast_exp2(s[ct][r] - st.m[r]);   // bounded by 2^THR
      s[ct][r] = p;
      rs += p;
    }
    rs = red16_sum(rs);
    st.l[r] += rs;
  }

  // P -> per-wave LDS (A-frag layout source), swizzled cols
#pragma unroll
  for (int ct = 0; ct < 4; ++ct)
#pragma unroll
    for (int r = 0; r < 4; ++r) {
      const int q = (seg << 2) + r;
      const int colp = ((ct << 4) + lq) ^ ((q & 7) << 3);
      Psw[q][colp] = (bf16)s[ct][r];
    }

  // PV: O += P[16][64] @ V[64][64]
  __builtin_amdgcn_s_setprio(1);
#pragma unroll
  for (int ks = 0; ks < 2; ++ks) {
    const int blkp = ((ks << 2) + seg) ^ (lq & 7);
    const bf16x8 af = *(const bf16x8*)(&Psw[lq][blkp << 3]);
#pragma unroll
    for (int dt = 0; dt < 4; ++dt) {
      const int xv = (lq & 7) ^ (((dt << 1) + (lq >> 3)) & 7);
      const int blkv = ((ks << 2) + seg) ^ xv;
      const bf16x8 bv = *(const bf16x8*)(&Vt[(dt << 4) + lq][blkv << 3]);
      st.o[dt] = __builtin_amdgcn_mfma_f32_16x16x32_bf16(af, bv, st.o[dt], 0, 0, 0);
    }
  }
  __builtin_amdgcn_s_setprio(0);
}

__device__ __forceinline__ void qtile_store(
    const QTile& st, bf16* __restrict__ out, const int qb, const int h,
    const int ws, const int lq, const int seg)
{
  float rinv[4];
#pragma unroll
  for (int r = 0; r < 4; ++r) rinv[r] = 1.f / st.l[r];
#pragma unroll
  for (int dt = 0; dt < 4; ++dt)
#pragma unroll
    for (int r = 0; r < 4; ++r) {
      const int qrow = (qb << 6) + (ws << 4) + (seg << 2) + r;
      out[(size_t)qrow * DM + h * HD + (dt << 4) + lq] =
          (bf16)(st.o[dt][r] * rinv[r]);
    }
}

// ---------------------------------------------------------------------------
// Flash-style causal attention, 8-wave blocks, UNIFORM 17-step schedule:
// B-waves (4-7) do B-tile KV 0..16; A-waves (0-3) do A-tile KV 0..qbA then
// B-tile KV 17..qbB as a second partial (split-K), merged in LDS at the end.
// (qbA+1)+(qbB+1)=33 always -> every block runs exactly 17 barrier-steps.
// Two KV tile streams, each double-buffered (S0: 0..16, S1: 17..qbB).
// XCD head-grouping keeps each XCD's KV in its private L2.
// ---------------------------------------------------------------------------
__global__ __launch_bounds__(512, 4) void attn_flash(
    const bf16* __restrict__ qkv, bf16* __restrict__ out)
{
  __shared__ __align__(16) bf16 Ks0[2][64][64];   // stream0 K (16 KB)
  __shared__ __align__(16) bf16 Vt0[2][64][64];   // stream0 V^T (16 KB)
  __shared__ __align__(16) bf16 Ks1[2][64][64];   // stream1 K
  __shared__ __align__(16) bf16 Vt1[2][64][64];   // stream1 V^T
  __shared__ __align__(16) bf16 Ps[8][16][64];    // per-wave P (16 KB)
  // XCD head-grouping: xcd = bid&7 serves heads 4*xcd..4*xcd+3
  const int bid = blockIdx.x;
  const int xcd = bid & 7, idx = bid >> 3;        // idx 0..63
  const int h   = (xcd << 2) | (idx >> 4);        // 4 heads per XCD
  const int qbA = idx & 15;                       // 0..15 (short tile)
  const int qbB = 31 - qbA;                       // 31..16 (long tile)
  const int tid = threadIdx.x;
  const int lane = tid & 63, wid = tid >> 6;      // wid 0..7
  const int lq = lane & 15, seg = lane >> 4;
  const bool isA = (wid < 4);
  const int ws   = wid & 3;                       // 16-row slice within tile

  const bf16* Kg = qkv + DM + h * HD;
  const bf16* Vg = qkv + 2 * DM + h * HD;

  // stP: A-waves = A-tile result; B-waves = B-front partial (tiles 0..16).
  // stS: A-waves only = B-back partial (tiles 17..qbB).
  QTile stP, stS;
  qtile_init(stP, qkv + (size_t)((isA ? qbA : qbB) * 64 + ws * 16) * QKV_LD + h * HD,
             lq, seg);
  if (isA)
    qtile_init(stS, qkv + (size_t)(qbB * 64 + ws * 16) * QKV_LD + h * HD, lq, seg);

  const int srow = tid >> 3, sch = tid & 7;  // staging: row 0..63, chunk 0..7

  // prologue: tile 0 -> S0 buf 0
  {
    const bf16x8 k0 = *(const bf16x8*)(Kg + (size_t)srow * QKV_LD + (sch << 3));
    const bf16x8 v0 = *(const bf16x8*)(Vg + (size_t)srow * QKV_LD + (sch << 3));
    *(bf16x8*)(&Ks0[0][srow][(sch ^ (srow & 7)) << 3]) = k0;
#pragma unroll
    for (int j = 0; j < 8; ++j)
      Vt0[0][(sch << 3) + j][srow ^ ((j ^ sch) << 3)] = v0[j];
  }
  __syncthreads();

  for (int t = 0; t <= 16; ++t) {
    // ---- issue next-step loads (block-uniform conditions; fly over compute)
    const bool st0 = (t < 16);                     // stream0: tile t+1
    const bool st1 = (t >= qbA && t <= 14);        // stream1: tile 17+(t-qbA)
    bf16x8 kr0, vr0, kr1, vr1;
    if (st0) {
      const int row = ((t + 1) << 6) + srow;
      kr0 = *(const bf16x8*)(Kg + (size_t)row * QKV_LD + (sch << 3));
      vr0 = *(const bf16x8*)(Vg + (size_t)row * QKV_LD + (sch << 3));
    }
    if (st1) {
      const int row = ((17 + (t - qbA)) << 6) + srow;
      kr1 = *(const bf16x8*)(Kg + (size_t)row * QKV_LD + (sch << 3));
      vr1 = *(const bf16x8*)(Vg + (size_t)row * QKV_LD + (sch << 3));
    }

    // ---- compute this step
    if (isA) {
      if (t <= qbA) {
        qtile_step(stP, qbA, t, ws, lq, seg, Ks0[t & 1], Vt0[t & 1], Ps[wid]);
      } else {
        const int nt1 = 16 + t - qbA;              // 17 .. qbB
        if (nt1 <= qbB)
          qtile_step(stS, qbB, nt1, ws, lq, seg,
                     Ks1[(t - qbA - 1) & 1], Vt1[(t - qbA - 1) & 1], Ps[wid]);
      }
    } else {
      qtile_step(stP, qbB, t, ws, lq, seg, Ks0[t & 1], Vt0[t & 1], Ps[wid]);
    }

    // ---- write-late: land next-step tiles (targets' readers ended last barrier)
    if (st0) {
      const int b = (t + 1) & 1;
      *(bf16x8*)(&Ks0[b][srow][(sch ^ (srow & 7)) << 3]) = kr0;
#pragma unroll
      for (int j = 0; j < 8; ++j)
        Vt0[b][(sch << 3) + j][srow ^ ((j ^ sch) << 3)] = vr0[j];
    }
    if (st1) {
      const int b = (t - qbA) & 1;
      *(bf16x8*)(&Ks1[b][srow][(sch ^ (srow & 7)) << 3]) = kr1;
#pragma unroll
      for (int j = 0; j < 8; ++j)
        Vt1[b][(sch << 3) + j][srow ^ ((j ^ sch) << 3)] = vr1[j];
    }
    __syncthreads();
  }

  // ---- epilogue: A-waves store A-tile; B-partials merge via LDS scratch
  float* so  = (float*)&Ks0[0][0][0];   // 4 waves x 64 lanes x 16 f32 = 16 KB
  float* sml = (float*)&Vt0[0][0][0];   // 4 waves x 64 lanes x 8  f32 =  8 KB
  const int sbase = (ws << 6) + lane;
  if (isA) {
    qtile_store(stP, out, qbA, h, ws, lq, seg);
#pragma unroll
    for (int dt = 0; dt < 4; ++dt)
#pragma unroll
      for (int r = 0; r < 4; ++r)
        so[sbase * 16 + (dt << 2) + r] = stS.o[dt][r];
#pragma unroll
    for (int r = 0; r < 4; ++r) {
      sml[sbase * 8 + r]     = stS.m[r];
      sml[sbase * 8 + 4 + r] = stS.l[r];
    }
  }
  __syncthreads();
  if (!isA) {
#pragma unroll
    for (int r = 0; r < 4; ++r) {
      const float pm = sml[sbase * 8 + r];
      const float pl = sml[sbase * 8 + 4 + r];
      const float mf = fmaxf(stP.m[r], pm);
      const float a  = fast_exp2(stP.m[r] - mf);
      const float b  = fast_exp2(pm - mf);      // 0 if partial empty (pm=-1e30)
      stP.m[r] = mf;
      stP.l[r] = stP.l[r] * a + pl * b;
#pragma unroll
      for (int dt = 0; dt < 4; ++dt)
        stP.o[dt][r] = stP.o[dt][r] * a + so[sbase * 16 + (dt << 2) + r] * b;
    }
    qtile_store(stP, out, qbB, h, ws, lq, seg);
  }
}

// ---------------------------------------------------------------------------
extern "C" void kernel_launch(void* const* d_in, const int* in_sizes, int n_in,
                              void* d_out, int out_size, void* d_ws, size_t ws_size,
                              hipStream_t stream) {
  (void)in_sizes; (void)n_in; (void)out_size; (void)ws_size;
  const float* hidden = (const float*)d_in[0];
  const float* w_qkv  = (const float*)d_in[1];
  const float* b_qkv  = (const float*)d_in[2];
  const float* w_out  = (const float*)d_in[3];
  const float* b_out  = (const float*)d_in[4];
  float* out = (float*)d_out;

  bf16* qkvbuf  = (bf16*)d_ws;                            // [2048][6144]
  bf16* attnbuf = qkvbuf  + (size_t)S_LEN * (3 * DM);     // [2048][2048]
  bf16* hidb    = attnbuf + (size_t)S_LEN * DM;           // [2048][2048]
  bf16* wqkvb   = hidb    + (size_t)S_LEN * DM;           // [6144][2048]
  bf16* woutb   = wqkvb   + (size_t)(3 * DM) * DM;        // [2048][2048]

  dim3 blk(256);
  // fused f32 -> bf16 conversions (one launch)
  cvt3_f32_bf16<<<dim3(2048), blk, 0, stream>>>(
      hidden, hidb, (S_LEN * DM) / 8,
      w_qkv, wqkvb, (3 * DM * DM) / 8,
      w_out, woutb, (DM * DM) / 8);
  // QKV projection: 128x192 tiles, 512 blocks = 2/CU, counted-vmcnt pipeline
  gemm_pipe<128, 192, 2, 4, 512, 4, bf16><<<dim3(32, 16), dim3(512), 0, stream>>>(
      hidb, wqkvb, b_qkv, qkvbuf, S_LEN, 3 * DM, DM);
  // Flash causal attention: uniform 17-step split-K pair blocks
  attn_flash<<<dim3(512), dim3(512), 0, stream>>>(qkvbuf, attnbuf);
  // Output projection: 64x128 tiles, 512 blocks = 2/CU, counted-vmcnt pipeline
  gemm_pipe<64, 128, 1, 4, 256, 2, float><<<dim3(16, 32), dim3(256), 0, stream>>>(
      attnbuf, woutb, b_out, out, S_LEN, DM, DM);
}

// Round 16
// 161.581 us; speedup vs baseline: 1.5168x; 1.5168x over previous
//
#include <hip/hip_runtime.h>
#include <hip/hip_bf16.h>

typedef __bf16 bf16;
typedef __attribute__((ext_vector_type(8))) __bf16 bf16x8;
typedef __attribute__((ext_vector_type(4))) float f32x4;

#define S_LEN 2048
#define DM 2048
#define NH 32
#define HD 64
#define QKV_LD 6144
// SCALE * log2(e): QK^T scores land directly in log2 domain
#define SCALE2 0.18033688011112042f
#define DEFER_THR 8.0f

// 2^x via v_exp_f32 (gfx9 v_exp IS base-2 exp).
__device__ __forceinline__ float fast_exp2(float x) {
  return __builtin_amdgcn_exp2f(x);
}

// Async global->LDS, 16B per lane. LDS dest must be wave-uniform base; data
// lands at base + lane*16.
__device__ __forceinline__ void gload_lds16(const bf16* g, const bf16* l) {
  __builtin_amdgcn_global_load_lds(
      (const __attribute__((address_space(1))) void*)(uintptr_t)g,
      (__attribute__((address_space(3))) void*)(uint32_t)(uintptr_t)l,
      16, 0, 0);
}

// Compile-time counted vmcnt (inline asm needs a literal).
template <int N>
__device__ __forceinline__ void waitcnt_vm() {
  if constexpr (N == 0)      asm volatile("s_waitcnt vmcnt(0)" ::: "memory");
  else if constexpr (N == 4) asm volatile("s_waitcnt vmcnt(4)" ::: "memory");
  else if constexpr (N == 5) asm volatile("s_waitcnt vmcnt(5)" ::: "memory");
  else if constexpr (N == 6) asm volatile("s_waitcnt vmcnt(6)" ::: "memory");
  else if constexpr (N == 7) asm volatile("s_waitcnt vmcnt(7)" ::: "memory");
  else if constexpr (N == 8) asm volatile("s_waitcnt vmcnt(8)" ::: "memory");
  else static_assert(N == 0, "add vmcnt case");
}

// DPP cross-lane move (VALU pipe — no LDS latency).
template <int CTRL>
__device__ __forceinline__ float fdpp(float x) {
  return __builtin_bit_cast(float,
      __builtin_amdgcn_update_dpp(0, __builtin_bit_cast(int, x), CTRL, 0xF, 0xF, true));
}
// Exact 16-lane butterfly all-reduce: masks {1,2,7,15} are GF(2)-independent.
__device__ __forceinline__ float red16_max(float x) {
  x = fmaxf(x, fdpp<0xB1>(x));    // quad_perm [1,0,3,2]  : xor 1
  x = fmaxf(x, fdpp<0x4E>(x));    // quad_perm [2,3,0,1]  : xor 2
  x = fmaxf(x, fdpp<0x141>(x));   // row_half_mirror      : xor 7
  x = fmaxf(x, fdpp<0x140>(x));   // row_mirror           : xor 15
  return x;
}
__device__ __forceinline__ float red16_sum(float x) {
  x += fdpp<0xB1>(x);
  x += fdpp<0x4E>(x);
  x += fdpp<0x141>(x);
  x += fdpp<0x140>(x);
  return x;
}

// ---------------------------------------------------------------------------
// Fused f32 -> bf16 conversion over three arrays (one launch, grid-stride)
// ---------------------------------------------------------------------------
__global__ __launch_bounds__(256) void cvt3_f32_bf16(
    const float* __restrict__ s0, bf16* __restrict__ d0, const int n0,
    const float* __restrict__ s1, bf16* __restrict__ d1, const int n1,
    const float* __restrict__ s2, bf16* __restrict__ d2, const int n2)
{
  const int total = n0 + n1 + n2;
  const int stride = gridDim.x * blockDim.x;
  for (int i = blockIdx.x * blockDim.x + threadIdx.x; i < total; i += stride) {
    const float* s; bf16* d; int j = i;
    if (j < n0)            { s = s0; d = d0; }
    else if (j - n0 < n1)  { s = s1; d = d1; j -= n0; }
    else                   { s = s2; d = d2; j -= n0 + n1; }
    const f32x4 a = *(const f32x4*)(s + (size_t)j * 8);
    const f32x4 b = *(const f32x4*)(s + (size_t)j * 8 + 4);
    bf16x8 r;
    r[0] = (bf16)a[0]; r[1] = (bf16)a[1]; r[2] = (bf16)a[2]; r[3] = (bf16)a[3];
    r[4] = (bf16)b[0]; r[5] = (bf16)b[1]; r[6] = (bf16)b[2]; r[7] = (bf16)b[3];
    *(bf16x8*)(d + (size_t)j * 8) = r;
  }
}

// ---------------------------------------------------------------------------
// Pipelined GEMM: C[M][N] = A @ W^T + bias.  BK=64, double-buffered LDS,
// depth-1 counted-vmcnt pipeline, T2 swizzle (rule #21), 2 blocks/CU.
// ---------------------------------------------------------------------------
template <int BM, int BN, int WRN, int WCN, int NT, int MINW, typename TO>
__global__ __launch_bounds__(NT, MINW) void gemm_pipe(
    const bf16* __restrict__ A, const bf16* __restrict__ W,
    const float* __restrict__ bias, TO* __restrict__ C,
    const int M, const int N, const int K)
{
  constexpr int WM = BM / WRN, WN = BN / WCN;
  constexpr int MI = WM / 16, NI = WN / 16;
  constexpr int CA = (BM * 64 * 2) / (NT * 16);   // staging chunks (A)
  constexpr int CB = (BN * 64 * 2) / (NT * 16);   // staging chunks (B)
  constexpr int BUFE = (BM + BN) * 64;            // elems per buffer
  __shared__ __align__(16) bf16 lds[2 * BUFE];
  const int tid  = threadIdx.x;
  const int lane = tid & 63;
  const int wid  = tid >> 6;
  const int wr = wid / WCN, wc = wid % WCN;
  const int row0 = blockIdx.y * BM, col0 = blockIdx.x * BN;
  const int lq = lane & 15, seg = lane >> 4;

  const f32x4 fz = {0.f, 0.f, 0.f, 0.f};
  f32x4 acc[MI][NI];
#pragma unroll
  for (int i = 0; i < MI; ++i)
#pragma unroll
    for (int j = 0; j < NI; ++j) acc[i][j] = fz;

  auto stage = [&](const int kt, const int b) {
    const int k0 = kt << 6;
    bf16* Ab = lds + b * BUFE;
    bf16* Bb = Ab + BM * 64;
#pragma unroll
    for (int c = 0; c < CA; ++c) {
      const int off16 = c * NT + tid;              // 16B-unit linear index
      const int row = off16 >> 3;                  // 128B rows (BK=64 bf16)
      const int ch  = (off16 & 7) ^ (row & 7);     // pre-swizzled source
      gload_lds16(A + (size_t)(row0 + row) * K + k0 + (ch << 3),
                  Ab + (size_t)(c * NT + (wid << 6)) * 8);
    }
#pragma unroll
    for (int c = 0; c < CB; ++c) {
      const int off16 = c * NT + tid;
      const int row = off16 >> 3;
      const int ch  = (off16 & 7) ^ (row & 7);
      gload_lds16(W + (size_t)(col0 + row) * K + k0 + (ch << 3),
                  Bb + (size_t)(c * NT + (wid << 6)) * 8);
    }
  };

  const int nt = K >> 6;
  stage(0, 0);

  for (int t = 0; t < nt; ++t) {
    asm volatile("" ::: "memory");
    __builtin_amdgcn_s_barrier();                  // frees buf (t+1)&1
    asm volatile("" ::: "memory");
    if (t + 1 < nt) {
      stage(t + 1, (t + 1) & 1);                   // loads fly across tile t
      waitcnt_vm<CA + CB>();                       // tile-t loads landed (mine)
    } else {
      waitcnt_vm<0>();                             // tail drain
    }
    __builtin_amdgcn_s_barrier();                  // tile t landed (all waves)
    asm volatile("" ::: "memory");

    const bf16* Ab = lds + (t & 1) * BUFE;
    const bf16* Bb = Ab + BM * 64;
#pragma unroll
    for (int kk = 0; kk < 2; ++kk) {               // K=64 as 2 x K32
      bf16x8 af[MI], bfr[NI];
#pragma unroll
      for (int i = 0; i < MI; ++i) {
        const int row = wr * WM + (i << 4) + lq;
        af[i] = *(const bf16x8*)(Ab + row * 64 +
                 ((((kk << 2) + seg) ^ (row & 7)) << 3));
      }
#pragma unroll
      for (int j = 0; j < NI; ++j) {
        const int row = wc * WN + (j << 4) + lq;
        bfr[j] = *(const bf16x8*)(Bb + row * 64 +
                 ((((kk << 2) + seg) ^ (row & 7)) << 3));
      }
      __builtin_amdgcn_s_setprio(1);
#pragma unroll
      for (int i = 0; i < MI; ++i)
#pragma unroll
        for (int j = 0; j < NI; ++j)
          acc[i][j] = __builtin_amdgcn_mfma_f32_16x16x32_bf16(af[i], bfr[j], acc[i][j], 0, 0, 0);
      __builtin_amdgcn_s_setprio(0);
    }
  }

  // Epilogue: C/D layout row=(lane>>4)*4+r, col=lane&15
#pragma unroll
  for (int j = 0; j < NI; ++j) {
    const int col = col0 + wc * WN + (j << 4) + lq;
    const float bv = bias[col];
#pragma unroll
    for (int i = 0; i < MI; ++i) {
      const int rbase = row0 + wr * WM + (i << 4) + (seg << 2);
#pragma unroll
      for (int r = 0; r < 4; ++r)
        C[(size_t)(rbase + r) * N + col] = (TO)(acc[i][j][r] + bv);
    }
  }
}

// ---------------------------------------------------------------------------
// Per-q-tile flash state (one 16-row slice per wave).
// ---------------------------------------------------------------------------
struct QTile {
  bf16x8 qf[2];    // pre-scaled by SCALE*log2e
  f32x4  o[4];
  float  m[4], l[4];
};

__device__ __forceinline__ void qtile_init(QTile& st, const bf16* Qg,
                                           const int lq, const int seg) {
  const bf16x8 r0 = *(const bf16x8*)(Qg + (size_t)lq * QKV_LD + seg * 8);
  const bf16x8 r1 = *(const bf16x8*)(Qg + (size_t)lq * QKV_LD + 32 + seg * 8);
#pragma unroll
  for (int j = 0; j < 8; ++j) {
    st.qf[0][j] = (bf16)((float)r0[j] * SCALE2);
    st.qf[1][j] = (bf16)((float)r1[j] * SCALE2);
  }
  const f32x4 fz = {0.f, 0.f, 0.f, 0.f};
#pragma unroll
  for (int r = 0; r < 4; ++r) { st.o[r] = fz; st.m[r] = -1e30f; st.l[r] = 0.f; }
}

// QK^T -> mask -> online softmax (log2 domain, defer-max) -> P -> PV.
__device__ __forceinline__ void qtile_step(
    QTile& st, const int qb, const int nt,
    const int ws, const int lq, const int seg,
    const bf16 (&Ks)[64][64], const bf16 (&Vt)[64][64], bf16 (&Psw)[16][64])
{
  const f32x4 fz = {0.f, 0.f, 0.f, 0.f};
  f32x4 s[4];
  __builtin_amdgcn_s_setprio(1);
#pragma unroll
  for (int ct = 0; ct < 4; ++ct) {
    s[ct] = fz;
#pragma unroll
    for (int ks = 0; ks < 2; ++ks) {
      const int blk = ((ks << 2) + seg) ^ (lq & 7);
      const bf16x8 kf = *(const bf16x8*)(&Ks[(ct << 4) + lq][blk << 3]);
      s[ct] = __builtin_amdgcn_mfma_f32_16x16x32_bf16(st.qf[ks], kf, s[ct], 0, 0, 0);
    }
  }
  __builtin_amdgcn_s_setprio(0);

  // causal mask (diagonal tile only); scores already scaled via Q
  if (nt == qb) {
#pragma unroll
    for (int ct = 0; ct < 4; ++ct) {
      const int key = (nt << 6) + (ct << 4) + lq;
#pragma unroll
      for (int r = 0; r < 4; ++r) {
        const int qrow = (qb << 6) + (ws << 4) + (seg << 2) + r;
        if (key > qrow) s[ct][r] = -1e30f;
      }
    }
  }

  // online softmax, log2 domain, defer-max (skip rescale within THR)
#pragma unroll
  for (int r = 0; r < 4; ++r) {
    float tm = fmaxf(fmaxf(s[0][r], s[1][r]), fmaxf(s[2][r], s[3][r]));
    tm = red16_max(tm);
    if (tm > st.m[r] + DEFER_THR) {      // rescale path (rare)
      const float sc = fast_exp2(st.m[r] - tm);
      st.m[r] = tm;
      st.l[r] *= sc;
#pragma unroll
      for (int dt = 0; dt < 4; ++dt) st.o[dt][r] *= sc;
    }
    float rs = 0.f;
#pragma unroll
    for (int ct = 0; ct < 4; ++ct) {
      const float p = fast_exp2(s[ct][r] - st.m[r]);   // bounded by 2^THR
      s[ct][r] = p;
      rs += p;
    }
    rs = red16_sum(rs);
    st.l[r] += rs;
  }

  // P -> per-wave LDS (A-frag layout source), swizzled cols
#pragma unroll
  for (int ct = 0; ct < 4; ++ct)
#pragma unroll
    for (int r = 0; r < 4; ++r) {
      const int q = (seg << 2) + r;
      const int colp = ((ct << 4) + lq) ^ ((q & 7) << 3);
      Psw[q][colp] = (bf16)s[ct][r];
    }

  // PV: O += P[16][64] @ V[64][64]
  __builtin_amdgcn_s_setprio(1);
#pragma unroll
  for (int ks = 0; ks < 2; ++ks) {
    const int blkp = ((ks << 2) + seg) ^ (lq & 7);
    const bf16x8 af = *(const bf16x8*)(&Psw[lq][blkp << 3]);
#pragma unroll
    for (int dt = 0; dt < 4; ++dt) {
      const int xv = (lq & 7) ^ (((dt << 1) + (lq >> 3)) & 7);
      const int blkv = ((ks << 2) + seg) ^ xv;
      const bf16x8 bv = *(const bf16x8*)(&Vt[(dt << 4) + lq][blkv << 3]);
      st.o[dt] = __builtin_amdgcn_mfma_f32_16x16x32_bf16(af, bv, st.o[dt], 0, 0, 0);
    }
  }
  __builtin_amdgcn_s_setprio(0);
}

__device__ __forceinline__ void qtile_store(
    const QTile& st, bf16* __restrict__ out, const int qb, const int h,
    const int ws, const int lq, const int seg)
{
  float rinv[4];
#pragma unroll
  for (int r = 0; r < 4; ++r) rinv[r] = 1.f / st.l[r];
#pragma unroll
  for (int dt = 0; dt < 4; ++dt)
#pragma unroll
    for (int r = 0; r < 4; ++r) {
      const int qrow = (qb << 6) + (ws << 4) + (seg << 2) + r;
      out[(size_t)qrow * DM + h * HD + (dt << 4) + lq] =
          (bf16)(st.o[dt][r] * rinv[r]);
    }
}

// ---------------------------------------------------------------------------
// Flash-style causal attention, 8-wave blocks, UNIFORM 17-step schedule:
// B-waves (4-7) do B-tile KV 0..16; A-waves (0-3) do A-tile KV 0..qbA then
// B-tile KV 17..qbB as a second partial (split-K), merged in LDS at the end.
// (qbA+1)+(qbB+1)=33 always -> every block runs exactly 17 barrier-steps.
// Two KV tile streams, each double-buffered (S0: 0..16, S1: 17..qbB).
// XCD head-grouping keeps each XCD's KV in its private L2.
// launch_bounds(512,2): 128-VGPR cap — R14's (512,4) forced a 64-VGPR cap
// and ~46 spilled regs/thread -> 290 MB scratch traffic (the regression).
// ---------------------------------------------------------------------------
__global__ __launch_bounds__(512, 2) void attn_flash(
    const bf16* __restrict__ qkv, bf16* __restrict__ out)
{
  __shared__ __align__(16) bf16 Ks0[2][64][64];   // stream0 K (16 KB)
  __shared__ __align__(16) bf16 Vt0[2][64][64];   // stream0 V^T (16 KB)
  __shared__ __align__(16) bf16 Ks1[2][64][64];   // stream1 K
  __shared__ __align__(16) bf16 Vt1[2][64][64];   // stream1 V^T
  __shared__ __align__(16) bf16 Ps[8][16][64];    // per-wave P (16 KB)
  // XCD head-grouping: xcd = bid&7 serves heads 4*xcd..4*xcd+3
  const int bid = blockIdx.x;
  const int xcd = bid & 7, idx = bid >> 3;        // idx 0..63
  const int h   = (xcd << 2) | (idx >> 4);        // 4 heads per XCD
  const int qbA = idx & 15;                       // 0..15 (short tile)
  const int qbB = 31 - qbA;                       // 31..16 (long tile)
  const int tid = threadIdx.x;
  const int lane = tid & 63, wid = tid >> 6;      // wid 0..7
  const int lq = lane & 15, seg = lane >> 4;
  const bool isA = (wid < 4);
  const int ws   = wid & 3;                       // 16-row slice within tile

  const bf16* Kg = qkv + DM + h * HD;
  const bf16* Vg = qkv + 2 * DM + h * HD;

  // stP: A-waves = A-tile result; B-waves = B-front partial (tiles 0..16).
  // stS: A-waves only = B-back partial (tiles 17..qbB).
  QTile stP, stS;
  qtile_init(stP, qkv + (size_t)((isA ? qbA : qbB) * 64 + ws * 16) * QKV_LD + h * HD,
             lq, seg);
  if (isA)
    qtile_init(stS, qkv + (size_t)(qbB * 64 + ws * 16) * QKV_LD + h * HD, lq, seg);

  const int srow = tid >> 3, sch = tid & 7;  // staging: row 0..63, chunk 0..7

  // prologue: tile 0 -> S0 buf 0
  {
    const bf16x8 k0 = *(const bf16x8*)(Kg + (size_t)srow * QKV_LD + (sch << 3));
    const bf16x8 v0 = *(const bf16x8*)(Vg + (size_t)srow * QKV_LD + (sch << 3));
    *(bf16x8*)(&Ks0[0][srow][(sch ^ (srow & 7)) << 3]) = k0;
#pragma unroll
    for (int j = 0; j < 8; ++j)
      Vt0[0][(sch << 3) + j][srow ^ ((j ^ sch) << 3)] = v0[j];
  }
  __syncthreads();

  for (int t = 0; t <= 16; ++t) {
    // ---- issue next-step loads (block-uniform conditions; fly over compute)
    const bool st0 = (t < 16);                     // stream0: tile t+1
    const bool st1 = (t >= qbA && t <= 14);        // stream1: tile 17+(t-qbA)
    bf16x8 kr0, vr0, kr1, vr1;
    if (st0) {
      const int row = ((t + 1) << 6) + srow;
      kr0 = *(const bf16x8*)(Kg + (size_t)row * QKV_LD + (sch << 3));
      vr0 = *(const bf16x8*)(Vg + (size_t)row * QKV_LD + (sch << 3));
    }
    if (st1) {
      const int row = ((17 + (t - qbA)) << 6) + srow;
      kr1 = *(const bf16x8*)(Kg + (size_t)row * QKV_LD + (sch << 3));
      vr1 = *(const bf16x8*)(Vg + (size_t)row * QKV_LD + (sch << 3));
    }

    // ---- compute this step
    if (isA) {
      if (t <= qbA) {
        qtile_step(stP, qbA, t, ws, lq, seg, Ks0[t & 1], Vt0[t & 1], Ps[wid]);
      } else {
        const int nt1 = 16 + t - qbA;              // 17 .. qbB
        if (nt1 <= qbB)
          qtile_step(stS, qbB, nt1, ws, lq, seg,
                     Ks1[(t - qbA - 1) & 1], Vt1[(t - qbA - 1) & 1], Ps[wid]);
      }
    } else {
      qtile_step(stP, qbB, t, ws, lq, seg, Ks0[t & 1], Vt0[t & 1], Ps[wid]);
    }

    // ---- write-late: land next-step tiles (targets' readers ended last barrier)
    if (st0) {
      const int b = (t + 1) & 1;
      *(bf16x8*)(&Ks0[b][srow][(sch ^ (srow & 7)) << 3]) = kr0;
#pragma unroll
      for (int j = 0; j < 8; ++j)
        Vt0[b][(sch << 3) + j][srow ^ ((j ^ sch) << 3)] = vr0[j];
    }
    if (st1) {
      const int b = (t - qbA) & 1;
      *(bf16x8*)(&Ks1[b][srow][(sch ^ (srow & 7)) << 3]) = kr1;
#pragma unroll
      for (int j = 0; j < 8; ++j)
        Vt1[b][(sch << 3) + j][srow ^ ((j ^ sch) << 3)] = vr1[j];
    }
    __syncthreads();
  }

  // ---- epilogue: A-waves store A-tile; B-partials merge via LDS scratch
  float* so  = (float*)&Ks0[0][0][0];   // 4 waves x 64 lanes x 16 f32 = 16 KB
  float* sml = (float*)&Vt0[0][0][0];   // 4 waves x 64 lanes x 8  f32 =  8 KB
  const int sbase = (ws << 6) + lane;
  if (isA) {
    qtile_store(stP, out, qbA, h, ws, lq, seg);
#pragma unroll
    for (int dt = 0; dt < 4; ++dt)
#pragma unroll
      for (int r = 0; r < 4; ++r)
        so[sbase * 16 + (dt << 2) + r] = stS.o[dt][r];
#pragma unroll
    for (int r = 0; r < 4; ++r) {
      sml[sbase * 8 + r]     = stS.m[r];
      sml[sbase * 8 + 4 + r] = stS.l[r];
    }
  }
  __syncthreads();
  if (!isA) {
#pragma unroll
    for (int r = 0; r < 4; ++r) {
      const float pm = sml[sbase * 8 + r];
      const float pl = sml[sbase * 8 + 4 + r];
      const float mf = fmaxf(stP.m[r], pm);
      const float a  = fast_exp2(stP.m[r] - mf);
      const float b  = fast_exp2(pm - mf);      // 0 if partial empty (pm=-1e30)
      stP.m[r] = mf;
      stP.l[r] = stP.l[r] * a + pl * b;
#pragma unroll
      for (int dt = 0; dt < 4; ++dt)
        stP.o[dt][r] = stP.o[dt][r] * a + so[sbase * 16 + (dt << 2) + r] * b;
    }
    qtile_store(stP, out, qbB, h, ws, lq, seg);
  }
}

// ---------------------------------------------------------------------------
extern "C" void kernel_launch(void* const* d_in, const int* in_sizes, int n_in,
                              void* d_out, int out_size, void* d_ws, size_t ws_size,
                              hipStream_t stream) {
  (void)in_sizes; (void)n_in; (void)out_size; (void)ws_size;
  const float* hidden = (const float*)d_in[0];
  const float* w_qkv  = (const float*)d_in[1];
  const float* b_qkv  = (const float*)d_in[2];
  const float* w_out  = (const float*)d_in[3];
  const float* b_out  = (const float*)d_in[4];
  float* out = (float*)d_out;

  bf16* qkvbuf  = (bf16*)d_ws;                            // [2048][6144]
  bf16* attnbuf = qkvbuf  + (size_t)S_LEN * (3 * DM);     // [2048][2048]
  bf16* hidb    = attnbuf + (size_t)S_LEN * DM;           // [2048][2048]
  bf16* wqkvb   = hidb    + (size_t)S_LEN * DM;           // [6144][2048]
  bf16* woutb   = wqkvb   + (size_t)(3 * DM) * DM;        // [2048][2048]

  dim3 blk(256);
  // fused f32 -> bf16 conversions (one launch)
  cvt3_f32_bf16<<<dim3(2048), blk, 0, stream>>>(
      hidden, hidb, (S_LEN * DM) / 8,
      w_qkv, wqkvb, (3 * DM * DM) / 8,
      w_out, woutb, (DM * DM) / 8);
  // QKV projection: 128x192 tiles, 512 blocks = 2/CU, counted-vmcnt pipeline
  gemm_pipe<128, 192, 2, 4, 512, 4, bf16><<<dim3(32, 16), dim3(512), 0, stream>>>(
      hidb, wqkvb, b_qkv, qkvbuf, S_LEN, 3 * DM, DM);
  // Flash causal attention: uniform 17-step split-K pair blocks
  attn_flash<<<dim3(512), dim3(512), 0, stream>>>(qkvbuf, attnbuf);
  // Output projection: 64x128 tiles, 512 blocks = 2/CU, counted-vmcnt pipeline
  gemm_pipe<64, 128, 1, 4, 256, 2, float><<<dim3(16, 32), dim3(256), 0, stream>>>(
      attnbuf, woutb, b_out, out, S_LEN, DM, DM);
}

// Round 17
// 147.884 us; speedup vs baseline: 1.6572x; 1.0926x over previous
//
#include <hip/hip_runtime.h>
#include <hip/hip_bf16.h>

typedef __bf16 bf16;
typedef __attribute__((ext_vector_type(8))) __bf16 bf16x8;
typedef __attribute__((ext_vector_type(4))) float f32x4;

#define S_LEN 2048
#define DM 2048
#define NH 32
#define HD 64
#define QKV_LD 6144
// SCALE * log2(e): QK^T scores land directly in log2 domain
#define SCALE2 0.18033688011112042f
#define DEFER_THR 8.0f

// 2^x via v_exp_f32 (gfx9 v_exp IS base-2 exp).
__device__ __forceinline__ float fast_exp2(float x) {
  return __builtin_amdgcn_exp2f(x);
}

// Async global->LDS, 16B per lane. LDS dest must be wave-uniform base; data
// lands at base + lane*16.
__device__ __forceinline__ void gload_lds16(const bf16* g, const bf16* l) {
  __builtin_amdgcn_global_load_lds(
      (const __attribute__((address_space(1))) void*)(uintptr_t)g,
      (__attribute__((address_space(3))) void*)(uint32_t)(uintptr_t)l,
      16, 0, 0);
}

// Compile-time counted vmcnt (inline asm needs a literal).
template <int N>
__device__ __forceinline__ void waitcnt_vm() {
  if constexpr (N == 0)      asm volatile("s_waitcnt vmcnt(0)" ::: "memory");
  else if constexpr (N == 4) asm volatile("s_waitcnt vmcnt(4)" ::: "memory");
  else if constexpr (N == 5) asm volatile("s_waitcnt vmcnt(5)" ::: "memory");
  else if constexpr (N == 6) asm volatile("s_waitcnt vmcnt(6)" ::: "memory");
  else if constexpr (N == 7) asm volatile("s_waitcnt vmcnt(7)" ::: "memory");
  else if constexpr (N == 8) asm volatile("s_waitcnt vmcnt(8)" ::: "memory");
  else static_assert(N == 0, "add vmcnt case");
}

// DPP cross-lane move (VALU pipe — no LDS latency).
template <int CTRL>
__device__ __forceinline__ float fdpp(float x) {
  return __builtin_bit_cast(float,
      __builtin_amdgcn_update_dpp(0, __builtin_bit_cast(int, x), CTRL, 0xF, 0xF, true));
}
// Exact 16-lane butterfly all-reduce: masks {1,2,7,15} are GF(2)-independent.
__device__ __forceinline__ float red16_max(float x) {
  x = fmaxf(x, fdpp<0xB1>(x));    // quad_perm [1,0,3,2]  : xor 1
  x = fmaxf(x, fdpp<0x4E>(x));    // quad_perm [2,3,0,1]  : xor 2
  x = fmaxf(x, fdpp<0x141>(x));   // row_half_mirror      : xor 7
  x = fmaxf(x, fdpp<0x140>(x));   // row_mirror           : xor 15
  return x;
}
__device__ __forceinline__ float red16_sum(float x) {
  x += fdpp<0xB1>(x);
  x += fdpp<0x4E>(x);
  x += fdpp<0x141>(x);
  x += fdpp<0x140>(x);
  return x;
}

// ---------------------------------------------------------------------------
// Fused f32 -> bf16 conversion over three arrays (one launch, grid-stride)
// ---------------------------------------------------------------------------
__global__ __launch_bounds__(256) void cvt3_f32_bf16(
    const float* __restrict__ s0, bf16* __restrict__ d0, const int n0,
    const float* __restrict__ s1, bf16* __restrict__ d1, const int n1,
    const float* __restrict__ s2, bf16* __restrict__ d2, const int n2)
{
  const int total = n0 + n1 + n2;
  const int stride = gridDim.x * blockDim.x;
  for (int i = blockIdx.x * blockDim.x + threadIdx.x; i < total; i += stride) {
    const float* s; bf16* d; int j = i;
    if (j < n0)            { s = s0; d = d0; }
    else if (j - n0 < n1)  { s = s1; d = d1; j -= n0; }
    else                   { s = s2; d = d2; j -= n0 + n1; }
    const f32x4 a = *(const f32x4*)(s + (size_t)j * 8);
    const f32x4 b = *(const f32x4*)(s + (size_t)j * 8 + 4);
    bf16x8 r;
    r[0] = (bf16)a[0]; r[1] = (bf16)a[1]; r[2] = (bf16)a[2]; r[3] = (bf16)a[3];
    r[4] = (bf16)b[0]; r[5] = (bf16)b[1]; r[6] = (bf16)b[2]; r[7] = (bf16)b[3];
    *(bf16x8*)(d + (size_t)j * 8) = r;
  }
}

// ---------------------------------------------------------------------------
// Pipelined GEMM: C[M][N] = A @ W^T + bias.  BK=64, double-buffered LDS,
// depth-1 counted-vmcnt pipeline, T2 swizzle (rule #21), 2 blocks/CU.
// MINW: empirically blocks/CU VGPR-cap target on this toolchain — must match
// what LDS allows (80KB dbuf -> 2), else the allocator spills for nothing.
// ---------------------------------------------------------------------------
template <int BM, int BN, int WRN, int WCN, int NT, int MINW, typename TO>
__global__ __launch_bounds__(NT, MINW) void gemm_pipe(
    const bf16* __restrict__ A, const bf16* __restrict__ W,
    const float* __restrict__ bias, TO* __restrict__ C,
    const int M, const int N, const int K)
{
  constexpr int WM = BM / WRN, WN = BN / WCN;
  constexpr int MI = WM / 16, NI = WN / 16;
  constexpr int CA = (BM * 64 * 2) / (NT * 16);   // staging chunks (A)
  constexpr int CB = (BN * 64 * 2) / (NT * 16);   // staging chunks (B)
  constexpr int BUFE = (BM + BN) * 64;            // elems per buffer
  __shared__ __align__(16) bf16 lds[2 * BUFE];
  const int tid  = threadIdx.x;
  const int lane = tid & 63;
  const int wid  = tid >> 6;
  const int wr = wid / WCN, wc = wid % WCN;
  const int row0 = blockIdx.y * BM, col0 = blockIdx.x * BN;
  const int lq = lane & 15, seg = lane >> 4;

  const f32x4 fz = {0.f, 0.f, 0.f, 0.f};
  f32x4 acc[MI][NI];
#pragma unroll
  for (int i = 0; i < MI; ++i)
#pragma unroll
    for (int j = 0; j < NI; ++j) acc[i][j] = fz;

  auto stage = [&](const int kt, const int b) {
    const int k0 = kt << 6;
    bf16* Ab = lds + b * BUFE;
    bf16* Bb = Ab + BM * 64;
#pragma unroll
    for (int c = 0; c < CA; ++c) {
      const int off16 = c * NT + tid;              // 16B-unit linear index
      const int row = off16 >> 3;                  // 128B rows (BK=64 bf16)
      const int ch  = (off16 & 7) ^ (row & 7);     // pre-swizzled source
      gload_lds16(A + (size_t)(row0 + row) * K + k0 + (ch << 3),
                  Ab + (size_t)(c * NT + (wid << 6)) * 8);
    }
#pragma unroll
    for (int c = 0; c < CB; ++c) {
      const int off16 = c * NT + tid;
      const int row = off16 >> 3;
      const int ch  = (off16 & 7) ^ (row & 7);
      gload_lds16(W + (size_t)(col0 + row) * K + k0 + (ch << 3),
                  Bb + (size_t)(c * NT + (wid << 6)) * 8);
    }
  };

  const int nt = K >> 6;
  stage(0, 0);

  for (int t = 0; t < nt; ++t) {
    asm volatile("" ::: "memory");
    __builtin_amdgcn_s_barrier();                  // frees buf (t+1)&1
    asm volatile("" ::: "memory");
    if (t + 1 < nt) {
      stage(t + 1, (t + 1) & 1);                   // loads fly across tile t
      waitcnt_vm<CA + CB>();                       // tile-t loads landed (mine)
    } else {
      waitcnt_vm<0>();                             // tail drain
    }
    __builtin_amdgcn_s_barrier();                  // tile t landed (all waves)
    asm volatile("" ::: "memory");

    const bf16* Ab = lds + (t & 1) * BUFE;
    const bf16* Bb = Ab + BM * 64;
#pragma unroll
    for (int kk = 0; kk < 2; ++kk) {               // K=64 as 2 x K32
      bf16x8 af[MI], bfr[NI];
#pragma unroll
      for (int i = 0; i < MI; ++i) {
        const int row = wr * WM + (i << 4) + lq;
        af[i] = *(const bf16x8*)(Ab + row * 64 +
                 ((((kk << 2) + seg) ^ (row & 7)) << 3));
      }
#pragma unroll
      for (int j = 0; j < NI; ++j) {
        const int row = wc * WN + (j << 4) + lq;
        bfr[j] = *(const bf16x8*)(Bb + row * 64 +
                 ((((kk << 2) + seg) ^ (row & 7)) << 3));
      }
      __builtin_amdgcn_s_setprio(1);
#pragma unroll
      for (int i = 0; i < MI; ++i)
#pragma unroll
        for (int j = 0; j < NI; ++j)
          acc[i][j] = __builtin_amdgcn_mfma_f32_16x16x32_bf16(af[i], bfr[j], acc[i][j], 0, 0, 0);
      __builtin_amdgcn_s_setprio(0);
    }
  }

  // Epilogue: C/D layout row=(lane>>4)*4+r, col=lane&15
#pragma unroll
  for (int j = 0; j < NI; ++j) {
    const int col = col0 + wc * WN + (j << 4) + lq;
    const float bv = bias[col];
#pragma unroll
    for (int i = 0; i < MI; ++i) {
      const int rbase = row0 + wr * WM + (i << 4) + (seg << 2);
#pragma unroll
      for (int r = 0; r < 4; ++r)
        C[(size_t)(rbase + r) * N + col] = (TO)(acc[i][j][r] + bv);
    }
  }
}

// ---------------------------------------------------------------------------
// Per-q-tile flash state (one 16-row slice per wave).
// ---------------------------------------------------------------------------
struct QTile {
  bf16x8 qf[2];    // pre-scaled by SCALE*log2e
  f32x4  o[4];
  float  m[4], l[4];
};

__device__ __forceinline__ void qtile_init(QTile& st, const bf16* Qg,
                                           const int lq, const int seg) {
  const bf16x8 r0 = *(const bf16x8*)(Qg + (size_t)lq * QKV_LD + seg * 8);
  const bf16x8 r1 = *(const bf16x8*)(Qg + (size_t)lq * QKV_LD + 32 + seg * 8);
#pragma unroll
  for (int j = 0; j < 8; ++j) {
    st.qf[0][j] = (bf16)((float)r0[j] * SCALE2);
    st.qf[1][j] = (bf16)((float)r1[j] * SCALE2);
  }
  const f32x4 fz = {0.f, 0.f, 0.f, 0.f};
#pragma unroll
  for (int r = 0; r < 4; ++r) { st.o[r] = fz; st.m[r] = -1e30f; st.l[r] = 0.f; }
}

// QK^T -> mask -> online softmax (log2 domain, defer-max) -> P -> PV.
__device__ __forceinline__ void qtile_step(
    QTile& st, const int qb, const int nt,
    const int ws, const int lq, const int seg,
    const bf16 (&Ks)[64][64], const bf16 (&Vt)[64][64], bf16 (&Psw)[16][64])
{
  const f32x4 fz = {0.f, 0.f, 0.f, 0.f};
  f32x4 s[4];
  __builtin_amdgcn_s_setprio(1);
#pragma unroll
  for (int ct = 0; ct < 4; ++ct) {
    s[ct] = fz;
#pragma unroll
    for (int ks = 0; ks < 2; ++ks) {
      const int blk = ((ks << 2) + seg) ^ (lq & 7);
      const bf16x8 kf = *(const bf16x8*)(&Ks[(ct << 4) + lq][blk << 3]);
      s[ct] = __builtin_amdgcn_mfma_f32_16x16x32_bf16(st.qf[ks], kf, s[ct], 0, 0, 0);
    }
  }
  __builtin_amdgcn_s_setprio(0);

  // causal mask (diagonal tile only); scores already scaled via Q
  if (nt == qb) {
#pragma unroll
    for (int ct = 0; ct < 4; ++ct) {
      const int key = (nt << 6) + (ct << 4) + lq;
#pragma unroll
      for (int r = 0; r < 4; ++r) {
        const int qrow = (qb << 6) + (ws << 4) + (seg << 2) + r;
        if (key > qrow) s[ct][r] = -1e30f;
      }
    }
  }

  // online softmax, log2 domain, defer-max (skip rescale within THR)
#pragma unroll
  for (int r = 0; r < 4; ++r) {
    float tm = fmaxf(fmaxf(s[0][r], s[1][r]), fmaxf(s[2][r], s[3][r]));
    tm = red16_max(tm);
    if (tm > st.m[r] + DEFER_THR) {      // rescale path (rare)
      const float sc = fast_exp2(st.m[r] - tm);
      st.m[r] = tm;
      st.l[r] *= sc;
#pragma unroll
      for (int dt = 0; dt < 4; ++dt) st.o[dt][r] *= sc;
    }
    float rs = 0.f;
#pragma unroll
    for (int ct = 0; ct < 4; ++ct) {
      const float p = fast_exp2(s[ct][r] - st.m[r]);   // bounded by 2^THR
      s[ct][r] = p;
      rs += p;
    }
    rs = red16_sum(rs);
    st.l[r] += rs;
  }

  // P -> per-wave LDS (A-frag layout source), swizzled cols
#pragma unroll
  for (int ct = 0; ct < 4; ++ct)
#pragma unroll
    for (int r = 0; r < 4; ++r) {
      const int q = (seg << 2) + r;
      const int colp = ((ct << 4) + lq) ^ ((q & 7) << 3);
      Psw[q][colp] = (bf16)s[ct][r];
    }

  // PV: O += P[16][64] @ V[64][64]
  __builtin_amdgcn_s_setprio(1);
#pragma unroll
  for (int ks = 0; ks < 2; ++ks) {
    const int blkp = ((ks << 2) + seg) ^ (lq & 7);
    const bf16x8 af = *(const bf16x8*)(&Psw[lq][blkp << 3]);
#pragma unroll
    for (int dt = 0; dt < 4; ++dt) {
      const int xv = (lq & 7) ^ (((dt << 1) + (lq >> 3)) & 7);
      const int blkv = ((ks << 2) + seg) ^ xv;
      const bf16x8 bv = *(const bf16x8*)(&Vt[(dt << 4) + lq][blkv << 3]);
      st.o[dt] = __builtin_amdgcn_mfma_f32_16x16x32_bf16(af, bv, st.o[dt], 0, 0, 0);
    }
  }
  __builtin_amdgcn_s_setprio(0);
}

__device__ __forceinline__ void qtile_store(
    const QTile& st, bf16* __restrict__ out, const int qb, const int h,
    const int ws, const int lq, const int seg)
{
  float rinv[4];
#pragma unroll
  for (int r = 0; r < 4; ++r) rinv[r] = 1.f / st.l[r];
#pragma unroll
  for (int dt = 0; dt < 4; ++dt)
#pragma unroll
    for (int r = 0; r < 4; ++r) {
      const int qrow = (qb << 6) + (ws << 4) + (seg << 2) + r;
      out[(size_t)qrow * DM + h * HD + (dt << 4) + lq] =
          (bf16)(st.o[dt][r] * rinv[r]);
    }
}

// ---------------------------------------------------------------------------
// Flash-style causal attention, 8-wave blocks, wrap-paired q-tiles,
// XCD head-grouping (each XCD owns 4 heads -> KV stays in its L2),
// double-buffered KV with ONE barrier per tile (T14 write-late split).
// [R13 structure — static balance via pairing; verified 58.1 us.]
// ---------------------------------------------------------------------------
__global__ __launch_bounds__(512, 4) void attn_flash(
    const bf16* __restrict__ qkv, bf16* __restrict__ out)
{
  __shared__ __align__(16) bf16 Ks[2][64][64];    // [buf][key][d], col-swizzled
  __shared__ __align__(16) bf16 Vt[2][64][64];    // [buf][d][key], key-swizzled
  __shared__ __align__(16) bf16 Ps[8][16][64];    // per-wave P, col-swizzled
  // XCD head-grouping: xcd = bid&7 serves heads 4*xcd..4*xcd+3
  const int bid = blockIdx.x;
  const int xcd = bid & 7, idx = bid >> 3;        // idx 0..63
  const int h   = (xcd << 2) | (idx >> 4);        // 4 heads per XCD
  const int qbA = idx & 15;                       // 0..15 (short range)
  const int qbB = 31 - qbA;                       // 31..16 (long range)
  const int tid = threadIdx.x;
  const int lane = tid & 63, wid = tid >> 6;      // wid 0..7
  const int lq = lane & 15, seg = lane >> 4;
  const int myqb = (wid < 4) ? qbA : qbB;
  const int ws   = wid & 3;                       // 16-row slice within tile

  const bf16* Kg = qkv + DM + h * HD;
  const bf16* Vg = qkv + 2 * DM + h * HD;

  QTile st;
  qtile_init(st, qkv + (size_t)(myqb * 64 + ws * 16) * QKV_LD + h * HD, lq, seg);

  const int srow = tid >> 3, sch = tid & 7;  // staging: row 0..63, chunk 0..7

  // prologue: tile 0 -> buf 0
  {
    const bf16x8 k0 = *(const bf16x8*)(Kg + (size_t)srow * QKV_LD + (sch << 3));
    const bf16x8 v0 = *(const bf16x8*)(Vg + (size_t)srow * QKV_LD + (sch << 3));
    *(bf16x8*)(&Ks[0][srow][(sch ^ (srow & 7)) << 3]) = k0;
#pragma unroll
    for (int j = 0; j < 8; ++j)
      Vt[0][(sch << 3) + j][srow ^ ((j ^ sch) << 3)] = v0[j];
  }
  __syncthreads();

  for (int nt = 0; nt <= qbB; ++nt) {
    // ---- issue next tile's global loads (fly during compute)
    bf16x8 kr, vr;
    if (nt < qbB) {
      const int row = ((nt + 1) << 6) + srow;
      kr = *(const bf16x8*)(Kg + (size_t)row * QKV_LD + (sch << 3));
      vr = *(const bf16x8*)(Vg + (size_t)row * QKV_LD + (sch << 3));
    }

    // ---- compute tile nt from buf[nt&1]
    if (nt <= myqb)
      qtile_step(st, myqb, nt, ws, lq, seg, Ks[nt & 1], Vt[nt & 1], Ps[wid]);

    // ---- write tile nt+1 into buf[(nt+1)&1] (reads of it ended last barrier)
    if (nt < qbB) {
      const int b = (nt + 1) & 1;
      *(bf16x8*)(&Ks[b][srow][(sch ^ (srow & 7)) << 3]) = kr;
#pragma unroll
      for (int j = 0; j < 8; ++j)
        Vt[b][(sch << 3) + j][srow ^ ((j ^ sch) << 3)] = vr[j];
    }
    __syncthreads();   // writes visible; reads of buf[nt&1] complete
  }

  qtile_store(st, out, myqb, h, ws, lq, seg);
}

// ---------------------------------------------------------------------------
extern "C" void kernel_launch(void* const* d_in, const int* in_sizes, int n_in,
                              void* d_out, int out_size, void* d_ws, size_t ws_size,
                              hipStream_t stream) {
  (void)in_sizes; (void)n_in; (void)out_size; (void)ws_size;
  const float* hidden = (const float*)d_in[0];
  const float* w_qkv  = (const float*)d_in[1];
  const float* b_qkv  = (const float*)d_in[2];
  const float* w_out  = (const float*)d_in[3];
  const float* b_out  = (const float*)d_in[4];
  float* out = (float*)d_out;

  bf16* qkvbuf  = (bf16*)d_ws;                            // [2048][6144]
  bf16* attnbuf = qkvbuf  + (size_t)S_LEN * (3 * DM);     // [2048][2048]
  bf16* hidb    = attnbuf + (size_t)S_LEN * DM;           // [2048][2048]
  bf16* wqkvb   = hidb    + (size_t)S_LEN * DM;           // [6144][2048]
  bf16* woutb   = wqkvb   + (size_t)(3 * DM) * DM;        // [2048][2048]

  dim3 blk(256);
  // fused f32 -> bf16 conversions (one launch)
  cvt3_f32_bf16<<<dim3(2048), blk, 0, stream>>>(
      hidden, hidb, (S_LEN * DM) / 8,
      w_qkv, wqkvb, (3 * DM * DM) / 8,
      w_out, woutb, (DM * DM) / 8);
  // QKV projection: 128x192 tiles, 512 blocks = 2/CU, counted-vmcnt pipeline.
  // MINW=2 (not 4): LDS already caps at 2 blocks/CU; the old MINW=4 forced a
  // 64-VGPR cap (demand ~95) for an unattainable occupancy target.
  gemm_pipe<128, 192, 2, 4, 512, 2, bf16><<<dim3(32, 16), dim3(512), 0, stream>>>(
      hidb, wqkvb, b_qkv, qkvbuf, S_LEN, 3 * DM, DM);
  // Flash causal attention: XCD head-grouped, paired q-tiles, KV dbuf (R13)
  attn_flash<<<dim3(512), dim3(512), 0, stream>>>(qkvbuf, attnbuf);
  // Output projection: 64x128 tiles, 512 blocks = 2/CU, counted-vmcnt pipeline
  gemm_pipe<64, 128, 1, 4, 256, 2, float><<<dim3(16, 32), dim3(256), 0, stream>>>(
      attnbuf, woutb, b_out, out, S_LEN, DM, DM);
}

// Round 18
// 139.027 us; speedup vs baseline: 1.7628x; 1.0637x over previous
//
#include <hip/hip_runtime.h>
#include <hip/hip_bf16.h>

typedef __bf16 bf16;
typedef __attribute__((ext_vector_type(8))) __bf16 bf16x8;
typedef __attribute__((ext_vector_type(4))) float f32x4;

#define S_LEN 2048
#define DM 2048
#define NH 32
#define HD 64
#define QKV_LD 6144
// SCALE * log2(e): QK^T scores land directly in log2 domain
#define SCALE2 0.18033688011112042f
#define DEFER_THR 8.0f

// 2^x via v_exp_f32 (gfx9 v_exp IS base-2 exp).
__device__ __forceinline__ float fast_exp2(float x) {
  return __builtin_amdgcn_exp2f(x);
}

// Async global->LDS, 16B per lane. LDS dest must be wave-uniform base; data
// lands at base + lane*16.
__device__ __forceinline__ void gload_lds16(const bf16* g, const bf16* l) {
  __builtin_amdgcn_global_load_lds(
      (const __attribute__((address_space(1))) void*)(uintptr_t)g,
      (__attribute__((address_space(3))) void*)(uint32_t)(uintptr_t)l,
      16, 0, 0);
}

// Compile-time counted vmcnt (inline asm needs a literal).
template <int N>
__device__ __forceinline__ void waitcnt_vm() {
  if constexpr (N == 0)      asm volatile("s_waitcnt vmcnt(0)" ::: "memory");
  else if constexpr (N == 4) asm volatile("s_waitcnt vmcnt(4)" ::: "memory");
  else if constexpr (N == 5) asm volatile("s_waitcnt vmcnt(5)" ::: "memory");
  else if constexpr (N == 6) asm volatile("s_waitcnt vmcnt(6)" ::: "memory");
  else if constexpr (N == 7) asm volatile("s_waitcnt vmcnt(7)" ::: "memory");
  else if constexpr (N == 8) asm volatile("s_waitcnt vmcnt(8)" ::: "memory");
  else static_assert(N == 0, "add vmcnt case");
}

// DPP cross-lane move (VALU pipe — no LDS latency).
template <int CTRL>
__device__ __forceinline__ float fdpp(float x) {
  return __builtin_bit_cast(float,
      __builtin_amdgcn_update_dpp(0, __builtin_bit_cast(int, x), CTRL, 0xF, 0xF, true));
}
// Exact 16-lane butterfly all-reduce: masks {1,2,7,15} are GF(2)-independent.
__device__ __forceinline__ float red16_max(float x) {
  x = fmaxf(x, fdpp<0xB1>(x));    // quad_perm [1,0,3,2]  : xor 1
  x = fmaxf(x, fdpp<0x4E>(x));    // quad_perm [2,3,0,1]  : xor 2
  x = fmaxf(x, fdpp<0x141>(x));   // row_half_mirror      : xor 7
  x = fmaxf(x, fdpp<0x140>(x));   // row_mirror           : xor 15
  return x;
}

// ---------------------------------------------------------------------------
// Fused f32 -> bf16 conversion over three arrays (one launch, grid-stride)
// ---------------------------------------------------------------------------
__global__ __launch_bounds__(256) void cvt3_f32_bf16(
    const float* __restrict__ s0, bf16* __restrict__ d0, const int n0,
    const float* __restrict__ s1, bf16* __restrict__ d1, const int n1,
    const float* __restrict__ s2, bf16* __restrict__ d2, const int n2)
{
  const int total = n0 + n1 + n2;
  const int stride = gridDim.x * blockDim.x;
  for (int i = blockIdx.x * blockDim.x + threadIdx.x; i < total; i += stride) {
    const float* s; bf16* d; int j = i;
    if (j < n0)            { s = s0; d = d0; }
    else if (j - n0 < n1)  { s = s1; d = d1; j -= n0; }
    else                   { s = s2; d = d2; j -= n0 + n1; }
    const f32x4 a = *(const f32x4*)(s + (size_t)j * 8);
    const f32x4 b = *(const f32x4*)(s + (size_t)j * 8 + 4);
    bf16x8 r;
    r[0] = (bf16)a[0]; r[1] = (bf16)a[1]; r[2] = (bf16)a[2]; r[3] = (bf16)a[3];
    r[4] = (bf16)b[0]; r[5] = (bf16)b[1]; r[6] = (bf16)b[2]; r[7] = (bf16)b[3];
    *(bf16x8*)(d + (size_t)j * 8) = r;
  }
}

// ---------------------------------------------------------------------------
// Pipelined GEMM: C[M][N] = A @ W^T + bias.  BK=64, double-buffered LDS,
// depth-1 counted-vmcnt pipeline, T2 swizzle (rule #21), 2 blocks/CU.
// ---------------------------------------------------------------------------
template <int BM, int BN, int WRN, int WCN, int NT, int MINW, typename TO>
__global__ __launch_bounds__(NT, MINW) void gemm_pipe(
    const bf16* __restrict__ A, const bf16* __restrict__ W,
    const float* __restrict__ bias, TO* __restrict__ C,
    const int M, const int N, const int K)
{
  constexpr int WM = BM / WRN, WN = BN / WCN;
  constexpr int MI = WM / 16, NI = WN / 16;
  constexpr int CA = (BM * 64 * 2) / (NT * 16);   // staging chunks (A)
  constexpr int CB = (BN * 64 * 2) / (NT * 16);   // staging chunks (B)
  constexpr int BUFE = (BM + BN) * 64;            // elems per buffer
  __shared__ __align__(16) bf16 lds[2 * BUFE];
  const int tid  = threadIdx.x;
  const int lane = tid & 63;
  const int wid  = tid >> 6;
  const int wr = wid / WCN, wc = wid % WCN;
  const int row0 = blockIdx.y * BM, col0 = blockIdx.x * BN;
  const int lq = lane & 15, seg = lane >> 4;

  const f32x4 fz = {0.f, 0.f, 0.f, 0.f};
  f32x4 acc[MI][NI];
#pragma unroll
  for (int i = 0; i < MI; ++i)
#pragma unroll
    for (int j = 0; j < NI; ++j) acc[i][j] = fz;

  auto stage = [&](const int kt, const int b) {
    const int k0 = kt << 6;
    bf16* Ab = lds + b * BUFE;
    bf16* Bb = Ab + BM * 64;
#pragma unroll
    for (int c = 0; c < CA; ++c) {
      const int off16 = c * NT + tid;              // 16B-unit linear index
      const int row = off16 >> 3;                  // 128B rows (BK=64 bf16)
      const int ch  = (off16 & 7) ^ (row & 7);     // pre-swizzled source
      gload_lds16(A + (size_t)(row0 + row) * K + k0 + (ch << 3),
                  Ab + (size_t)(c * NT + (wid << 6)) * 8);
    }
#pragma unroll
    for (int c = 0; c < CB; ++c) {
      const int off16 = c * NT + tid;
      const int row = off16 >> 3;
      const int ch  = (off16 & 7) ^ (row & 7);
      gload_lds16(W + (size_t)(col0 + row) * K + k0 + (ch << 3),
                  Bb + (size_t)(c * NT + (wid << 6)) * 8);
    }
  };

  const int nt = K >> 6;
  stage(0, 0);

  for (int t = 0; t < nt; ++t) {
    asm volatile("" ::: "memory");
    __builtin_amdgcn_s_barrier();                  // frees buf (t+1)&1
    asm volatile("" ::: "memory");
    if (t + 1 < nt) {
      stage(t + 1, (t + 1) & 1);                   // loads fly across tile t
      waitcnt_vm<CA + CB>();                       // tile-t loads landed (mine)
    } else {
      waitcnt_vm<0>();                             // tail drain
    }
    __builtin_amdgcn_s_barrier();                  // tile t landed (all waves)
    asm volatile("" ::: "memory");

    const bf16* Ab = lds + (t & 1) * BUFE;
    const bf16* Bb = Ab + BM * 64;
#pragma unroll
    for (int kk = 0; kk < 2; ++kk) {               // K=64 as 2 x K32
      bf16x8 af[MI], bfr[NI];
#pragma unroll
      for (int i = 0; i < MI; ++i) {
        const int row = wr * WM + (i << 4) + lq;
        af[i] = *(const bf16x8*)(Ab + row * 64 +
                 ((((kk << 2) + seg) ^ (row & 7)) << 3));
      }
#pragma unroll
      for (int j = 0; j < NI; ++j) {
        const int row = wc * WN + (j << 4) + lq;
        bfr[j] = *(const bf16x8*)(Bb + row * 64 +
                 ((((kk << 2) + seg) ^ (row & 7)) << 3));
      }
      __builtin_amdgcn_s_setprio(1);
#pragma unroll
      for (int i = 0; i < MI; ++i)
#pragma unroll
        for (int j = 0; j < NI; ++j)
          acc[i][j] = __builtin_amdgcn_mfma_f32_16x16x32_bf16(af[i], bfr[j], acc[i][j], 0, 0, 0);
      __builtin_amdgcn_s_setprio(0);
    }
  }

  // Epilogue: C/D layout row=(lane>>4)*4+r, col=lane&15
#pragma unroll
  for (int j = 0; j < NI; ++j) {
    const int col = col0 + wc * WN + (j << 4) + lq;
    const float bv = bias[col];
#pragma unroll
    for (int i = 0; i < MI; ++i) {
      const int rbase = row0 + wr * WM + (i << 4) + (seg << 2);
#pragma unroll
      for (int r = 0; r < 4; ++r)
        C[(size_t)(rbase + r) * N + col] = (TO)(acc[i][j][r] + bv);
    }
  }
}

// ---------------------------------------------------------------------------
// Per-q-tile flash state (one 16-row slice per wave).
// m: ONE max per thread's 4-row group (any consistent per-row upper bound
// is a valid softmax anchor). ls: row-sums accumulated via ones-MFMA, same
// C-layout rows as o.
// ---------------------------------------------------------------------------
struct QTile {
  bf16x8 qf[2];    // pre-scaled by SCALE*log2e
  f32x4  o[4];
  f32x4  ls;       // l per row (from P @ ones)
  float  m;        // shared group max
};

__device__ __forceinline__ void qtile_init(QTile& st, const bf16* Qg,
                                           const int lq, const int seg) {
  const bf16x8 r0 = *(const bf16x8*)(Qg + (size_t)lq * QKV_LD + seg * 8);
  const bf16x8 r1 = *(const bf16x8*)(Qg + (size_t)lq * QKV_LD + 32 + seg * 8);
#pragma unroll
  for (int j = 0; j < 8; ++j) {
    st.qf[0][j] = (bf16)((float)r0[j] * SCALE2);
    st.qf[1][j] = (bf16)((float)r1[j] * SCALE2);
  }
  const f32x4 fz = {0.f, 0.f, 0.f, 0.f};
#pragma unroll
  for (int r = 0; r < 4; ++r) st.o[r] = fz;
  st.ls = fz;
  st.m = -1e30f;
}

// QK^T -> mask -> online softmax (log2, shared group max, defer-max) -> PV.
__device__ __forceinline__ void qtile_step(
    QTile& st, const int qb, const int nt,
    const int ws, const int lq, const int seg,
    const bf16 (&Ks)[64][64], const bf16 (&Vt)[64][64], bf16 (&Psw)[16][64])
{
  const f32x4 fz = {0.f, 0.f, 0.f, 0.f};
  f32x4 s[4];
  __builtin_amdgcn_s_setprio(1);
#pragma unroll
  for (int ct = 0; ct < 4; ++ct) {
    s[ct] = fz;
#pragma unroll
    for (int ks = 0; ks < 2; ++ks) {
      const int blk = ((ks << 2) + seg) ^ (lq & 7);
      const bf16x8 kf = *(const bf16x8*)(&Ks[(ct << 4) + lq][blk << 3]);
      s[ct] = __builtin_amdgcn_mfma_f32_16x16x32_bf16(st.qf[ks], kf, s[ct], 0, 0, 0);
    }
  }
  __builtin_amdgcn_s_setprio(0);

  // causal mask (diagonal tile only); scores already scaled via Q
  if (nt == qb) {
#pragma unroll
    for (int ct = 0; ct < 4; ++ct) {
      const int key = (nt << 6) + (ct << 4) + lq;
#pragma unroll
      for (int r = 0; r < 4; ++r) {
        const int qrow = (qb << 6) + (ws << 4) + (seg << 2) + r;
        if (key > qrow) s[ct][r] = -1e30f;
      }
    }
  }

  // shared group max (4 rows x 64 keys of this thread's lane-group)
  float tm = s[0][0];
#pragma unroll
  for (int ct = 0; ct < 4; ++ct)
#pragma unroll
    for (int r = 0; r < 4; ++r) tm = fmaxf(tm, s[ct][r]);
  tm = red16_max(tm);
  if (tm > st.m + DEFER_THR) {         // rescale path (rare)
    const float sc = fast_exp2(st.m - tm);
    st.m = tm;
    st.ls *= sc;
#pragma unroll
    for (int dt = 0; dt < 4; ++dt) st.o[dt] *= sc;
  }

  // P = exp2(s - m) -> per-wave LDS (A-frag layout), swizzled cols
#pragma unroll
  for (int ct = 0; ct < 4; ++ct)
#pragma unroll
    for (int r = 0; r < 4; ++r) {
      const int q = (seg << 2) + r;
      const int colp = ((ct << 4) + lq) ^ ((q & 7) << 3);
      Psw[q][colp] = (bf16)fast_exp2(s[ct][r] - st.m);
    }

  // PV: O += P @ V ; row-sums via ones-MFMA (replaces VALU butterfly sum)
  bf16x8 ones;
#pragma unroll
  for (int j = 0; j < 8; ++j) ones[j] = (bf16)1.0f;
  __builtin_amdgcn_s_setprio(1);
#pragma unroll
  for (int ks = 0; ks < 2; ++ks) {
    const int blkp = ((ks << 2) + seg) ^ (lq & 7);
    const bf16x8 af = *(const bf16x8*)(&Psw[lq][blkp << 3]);
    st.ls = __builtin_amdgcn_mfma_f32_16x16x32_bf16(af, ones, st.ls, 0, 0, 0);
#pragma unroll
    for (int dt = 0; dt < 4; ++dt) {
      const int xv = (lq & 7) ^ (((dt << 1) + (lq >> 3)) & 7);
      const int blkv = ((ks << 2) + seg) ^ xv;
      const bf16x8 bv = *(const bf16x8*)(&Vt[(dt << 4) + lq][blkv << 3]);
      st.o[dt] = __builtin_amdgcn_mfma_f32_16x16x32_bf16(af, bv, st.o[dt], 0, 0, 0);
    }
  }
  __builtin_amdgcn_s_setprio(0);
}

__device__ __forceinline__ void qtile_store(
    const QTile& st, bf16* __restrict__ out, const int qb, const int h,
    const int ws, const int lq, const int seg)
{
  float rinv[4];
#pragma unroll
  for (int r = 0; r < 4; ++r) rinv[r] = 1.f / st.ls[r];
#pragma unroll
  for (int dt = 0; dt < 4; ++dt)
#pragma unroll
    for (int r = 0; r < 4; ++r) {
      const int qrow = (qb << 6) + (ws << 4) + (seg << 2) + r;
      out[(size_t)qrow * DM + h * HD + (dt << 4) + lq] =
          (bf16)(st.o[dt][r] * rinv[r]);
    }
}

// ---------------------------------------------------------------------------
// Flash-style causal attention, 8-wave blocks, wrap-paired q-tiles,
// XCD head-grouping (each XCD owns 4 heads -> KV stays in its L2),
// double-buffered KV with ONE barrier per tile (T14 write-late split).
// ---------------------------------------------------------------------------
__global__ __launch_bounds__(512, 4) void attn_flash(
    const bf16* __restrict__ qkv, bf16* __restrict__ out)
{
  __shared__ __align__(16) bf16 Ks[2][64][64];    // [buf][key][d], col-swizzled
  __shared__ __align__(16) bf16 Vt[2][64][64];    // [buf][d][key], key-swizzled
  __shared__ __align__(16) bf16 Ps[8][16][64];    // per-wave P, col-swizzled
  // XCD head-grouping: xcd = bid&7 serves heads 4*xcd..4*xcd+3
  const int bid = blockIdx.x;
  const int xcd = bid & 7, idx = bid >> 3;        // idx 0..63
  const int h   = (xcd << 2) | (idx >> 4);        // 4 heads per XCD
  const int qbA = idx & 15;                       // 0..15 (short range)
  const int qbB = 31 - qbA;                       // 31..16 (long range)
  const int tid = threadIdx.x;
  const int lane = tid & 63, wid = tid >> 6;      // wid 0..7
  const int lq = lane & 15, seg = lane >> 4;
  const int myqb = (wid < 4) ? qbA : qbB;
  const int ws   = wid & 3;                       // 16-row slice within tile

  const bf16* Kg = qkv + DM + h * HD;
  const bf16* Vg = qkv + 2 * DM + h * HD;

  QTile st;
  qtile_init(st, qkv + (size_t)(myqb * 64 + ws * 16) * QKV_LD + h * HD, lq, seg);

  const int srow = tid >> 3, sch = tid & 7;  // staging: row 0..63, chunk 0..7

  // prologue: tile 0 -> buf 0
  {
    const bf16x8 k0 = *(const bf16x8*)(Kg + (size_t)srow * QKV_LD + (sch << 3));
    const bf16x8 v0 = *(const bf16x8*)(Vg + (size_t)srow * QKV_LD + (sch << 3));
    *(bf16x8*)(&Ks[0][srow][(sch ^ (srow & 7)) << 3]) = k0;
#pragma unroll
    for (int j = 0; j < 8; ++j)
      Vt[0][(sch << 3) + j][srow ^ ((j ^ sch) << 3)] = v0[j];
  }
  __syncthreads();

  for (int nt = 0; nt <= qbB; ++nt) {
    // ---- issue next tile's global loads (fly during compute)
    bf16x8 kr, vr;
    if (nt < qbB) {
      const int row = ((nt + 1) << 6) + srow;
      kr = *(const bf16x8*)(Kg + (size_t)row * QKV_LD + (sch << 3));
      vr = *(const bf16x8*)(Vg + (size_t)row * QKV_LD + (sch << 3));
    }

    // ---- compute tile nt from buf[nt&1]
    if (nt <= myqb)
      qtile_step(st, myqb, nt, ws, lq, seg, Ks[nt & 1], Vt[nt & 1], Ps[wid]);

    // ---- write tile nt+1 into buf[(nt+1)&1] (reads of it ended last barrier)
    if (nt < qbB) {
      const int b = (nt + 1) & 1;
      *(bf16x8*)(&Ks[b][srow][(sch ^ (srow & 7)) << 3]) = kr;
#pragma unroll
      for (int j = 0; j < 8; ++j)
        Vt[b][(sch << 3) + j][srow ^ ((j ^ sch) << 3)] = vr[j];
    }
    __syncthreads();   // writes visible; reads of buf[nt&1] complete
  }

  qtile_store(st, out, myqb, h, ws, lq, seg);
}

// ---------------------------------------------------------------------------
extern "C" void kernel_launch(void* const* d_in, const int* in_sizes, int n_in,
                              void* d_out, int out_size, void* d_ws, size_t ws_size,
                              hipStream_t stream) {
  (void)in_sizes; (void)n_in; (void)out_size; (void)ws_size;
  const float* hidden = (const float*)d_in[0];
  const float* w_qkv  = (const float*)d_in[1];
  const float* b_qkv  = (const float*)d_in[2];
  const float* w_out  = (const float*)d_in[3];
  const float* b_out  = (const float*)d_in[4];
  float* out = (float*)d_out;

  bf16* qkvbuf  = (bf16*)d_ws;                            // [2048][6144]
  bf16* attnbuf = qkvbuf  + (size_t)S_LEN * (3 * DM);     // [2048][2048]
  bf16* hidb    = attnbuf + (size_t)S_LEN * DM;           // [2048][2048]
  bf16* wqkvb   = hidb    + (size_t)S_LEN * DM;           // [6144][2048]
  bf16* woutb   = wqkvb   + (size_t)(3 * DM) * DM;        // [2048][2048]

  dim3 blk(256);
  // fused f32 -> bf16 conversions (one launch)
  cvt3_f32_bf16<<<dim3(2048), blk, 0, stream>>>(
      hidden, hidb, (S_LEN * DM) / 8,
      w_qkv, wqkvb, (3 * DM * DM) / 8,
      w_out, woutb, (DM * DM) / 8);
  // QKV projection: 128x192 tiles, 512 blocks = 2/CU, counted-vmcnt pipeline
  gemm_pipe<128, 192, 2, 4, 512, 2, bf16><<<dim3(32, 16), dim3(512), 0, stream>>>(
      hidb, wqkvb, b_qkv, qkvbuf, S_LEN, 3 * DM, DM);
  // Flash causal attention: XCD head-grouped, paired q-tiles, KV dbuf
  attn_flash<<<dim3(512), dim3(512), 0, stream>>>(qkvbuf, attnbuf);
  // Output projection: 64x128 tiles, 512 blocks = 2/CU, counted-vmcnt pipeline
  gemm_pipe<64, 128, 1, 4, 256, 2, float><<<dim3(16, 32), dim3(256), 0, stream>>>(
      attnbuf, woutb, b_out, out, S_LEN, DM, DM);
}